// Round 2
// baseline (546.177 us; speedup 1.0000x reference)
//
#include <hip/hip_runtime.h>
#include <stdint.h>

typedef __fp16 f16x2 __attribute__((ext_vector_type(2)));
typedef __fp16 f16x8 __attribute__((ext_vector_type(8)));
typedef float  f32x4 __attribute__((ext_vector_type(4)));

#define GLOBAL_AS __attribute__((address_space(1)))
#define LDS_AS    __attribute__((address_space(3)))

#define NN   8192
#define INC  256
#define OUTC 256
#define K2   2048                    // INC * RR
#define YTN  ((size_t)OUTC * NN)     // 2M elements

__device__ __forceinline__ void async_copy16(const void* g, void* l) {
    // 16B per lane; LDS dest = wave-uniform base + lane*16 (m97/m104 semantics)
    __builtin_amdgcn_global_load_lds((const GLOBAL_AS uint32_t*)g,
                                     (LDS_AS uint32_t*)l, 16, 0, 0);
}

__device__ __forceinline__ f16x8 cvt_f32x8_to_f16x8(f32x4 u0, f32x4 u1) {
    f16x8 out;
    f16x2* p = (f16x2*)&out;
    p[0] = __builtin_amdgcn_cvt_pkrtz(u0[0], u0[1]);
    p[1] = __builtin_amdgcn_cvt_pkrtz(u0[2], u0[3]);
    p[2] = __builtin_amdgcn_cvt_pkrtz(u1[0], u1[1]);
    p[3] = __builtin_amdgcn_cvt_pkrtz(u1[2], u1[3]);
    return out;
}

// ---------------------------------------------------------------------------
// W2T16[o][k] = sum_b w_rel[r,b] * w_bases[b,i,o],  k = i*8+r, f16 output.
// One block per o; thread i covers k = i*8..i*8+7 (contiguous f16x8 store).
// ---------------------------------------------------------------------------
__global__ void build_w2t16(const float* __restrict__ wb, const float* __restrict__ wr,
                            __fp16* __restrict__ W2T16) {
    int o = blockIdx.x;      // 0..255
    int i = threadIdx.x;     // 0..255
    float s[8];
#pragma unroll
    for (int r = 0; r < 8; ++r) s[r] = 0.f;
#pragma unroll
    for (int b = 0; b < 4; ++b) {
        float w = wb[((size_t)((b << 8) + i)) * OUTC + o];
#pragma unroll
        for (int r = 0; r < 8; ++r) s[r] = fmaf(wr[r * 4 + b], w, s[r]);
    }
    f16x8 out;
    f16x2* p = (f16x2*)&out;
    p[0] = __builtin_amdgcn_cvt_pkrtz(s[0], s[1]);
    p[1] = __builtin_amdgcn_cvt_pkrtz(s[2], s[3]);
    p[2] = __builtin_amdgcn_cvt_pkrtz(s[4], s[5]);
    p[3] = __builtin_amdgcn_cvt_pkrtz(s[6], s[7]);
    *reinterpret_cast<f16x8*>(&W2T16[(size_t)o * K2 + i * 8]) = out;
}

// ---------------------------------------------------------------------------
// GEMM1: yT_p[z][o][m] = W2T16[o][:] . x[m][:]   (M=256 rows=o, N=8192 cols=m)
//   A = W2T16 f16 [256][2048]  -> LDS (double-buffered, XOR-swizzled)
//   B = x      f32 [8192][2048] -> streamed global->VGPR, cvt_pkrtz to f16
// Tile 128x128x32, 256 thr / 4 waves (2x2), wave tile 64x64 (acc[4][4]).
// One barrier per K-step (stage-next-then-compute, minimum-2-phase recipe).
// LDS swizzle: position p of row r holds k-chunk (p ^ ((r>>1)&3)) [16B chunks].
// ---------------------------------------------------------------------------
__global__ __launch_bounds__(256, 2)
void gemm1_xstream(const __fp16* __restrict__ W2, const float* __restrict__ X,
                   float* __restrict__ Cp, int kPerSplit) {
    __shared__ __align__(16) __fp16 As[2][128 * 32];    // 8KB x2
    const int bm = blockIdx.x * 128;
    const int bn = blockIdx.y * 128;
    const int k0 = blockIdx.z * kPerSplit;

    const int tid  = threadIdx.x;
    const int lane = tid & 63;
    const int wave = tid >> 6;
    const int wm   = (wave >> 1) * 64;
    const int wn   = (wave & 1) * 64;
    const int quad = lane >> 4;
    const int l16  = lane & 15;

    f32x4 acc[4][4];
#pragma unroll
    for (int ti = 0; ti < 4; ++ti)
#pragma unroll
        for (int tj = 0; tj < 4; ++tj)
            acc[ti][tj] = (f32x4){0.f, 0.f, 0.f, 0.f};

    const int nt = kPerSplit / 32;
    int cur = 0;

    // prologue: stage buffer 0
    {
#pragma unroll
        for (int i = 0; i < 2; ++i) {
            int r0 = wave * 32 + i * 16;
            int r  = r0 + (lane >> 2);
            int c  = (lane & 3) ^ ((r >> 1) & 3);
            async_copy16(W2 + (size_t)(bm + r) * K2 + k0 + c * 8,
                         (char*)As[0] + r0 * 64);
        }
    }

    for (int t = 0; t < nt; ++t) {
        __syncthreads();   // buf[cur] staged (vmcnt drained); prev reads of buf[cur^1] done
        if (t + 1 < nt) {
            int kc = k0 + (t + 1) * 32;
#pragma unroll
            for (int i = 0; i < 2; ++i) {
                int r0 = wave * 32 + i * 16;
                int r  = r0 + (lane >> 2);
                int c  = (lane & 3) ^ ((r >> 1) & 3);
                async_copy16(W2 + (size_t)(bm + r) * K2 + kc + c * 8,
                             (char*)As[cur ^ 1] + r0 * 64);
            }
        }
        const int kc = k0 + t * 32;

        // stream B (x, f32) -> f16 fragments
        f16x8 bf[4];
#pragma unroll
        for (int j = 0; j < 4; ++j) {
            const float* g = X + (size_t)(bn + wn + j * 16 + l16) * K2 + kc + quad * 8;
            f32x4 u0 = *(const f32x4*)g;
            f32x4 u1 = *(const f32x4*)(g + 4);
            bf[j] = cvt_f32x8_to_f16x8(u0, u1);
        }
        // A fragments from swizzled LDS
        f16x8 af[4];
#pragma unroll
        for (int j = 0; j < 4; ++j) {
            int row = wm + j * 16 + l16;
            int p   = quad ^ ((row >> 1) & 3);
            af[j] = *(const f16x8*)(&As[cur][0] + row * 32 + p * 8);
        }
#pragma unroll
        for (int ti = 0; ti < 4; ++ti)
#pragma unroll
            for (int tj = 0; tj < 4; ++tj)
                acc[ti][tj] = __builtin_amdgcn_mfma_f32_16x16x32_f16(
                    af[ti], bf[tj], acc[ti][tj], 0, 0, 0);
        cur ^= 1;
    }

    float* Cz = Cp + (size_t)blockIdx.z * 256 * NN;
#pragma unroll
    for (int ti = 0; ti < 4; ++ti)
#pragma unroll
        for (int tj = 0; tj < 4; ++tj)
#pragma unroll
            for (int r = 0; r < 4; ++r) {
                int row = bm + wm + ti * 16 + quad * 4 + r;   // o
                int col = bn + wn + tj * 16 + l16;            // m
                Cz[(size_t)row * NN + col] = acc[ti][tj][r];
            }
}

// ---------------------------------------------------------------------------
// GEMM2: out_p[z][n][o] = a[n][:] . yT16[o][:]   (M=8192 rows=n, N=256 cols=o)
//   A = a    f32 [8192][8192] -> streamed global->VGPR, cvt to f16 (no reuse)
//   B = yT16 f16 [256][8192]  -> LDS (double-buffered, XOR-swizzled), full N
// Tile 128x256x32, 256 thr / 4 waves, wave tile 64x128 (acc[4][8]).
// One barrier per K-step. LDS 16KB x2.
// ---------------------------------------------------------------------------
__global__ __launch_bounds__(256, 2)
void gemm2_astream(const float* __restrict__ A, const __fp16* __restrict__ Y,
                   float* __restrict__ Cp, int kPerSplit) {
    __shared__ __align__(16) __fp16 Bs[2][256 * 32];    // 16KB x2
    const int bm = blockIdx.x * 128;
    const int k0 = blockIdx.z * kPerSplit;

    const int tid  = threadIdx.x;
    const int lane = tid & 63;
    const int wave = tid >> 6;
    const int wm   = (wave >> 1) * 64;    // 0 / 64
    const int wn   = (wave & 1) * 128;    // 0 / 128
    const int quad = lane >> 4;
    const int l16  = lane & 15;

    f32x4 acc[4][8];
#pragma unroll
    for (int ti = 0; ti < 4; ++ti)
#pragma unroll
        for (int tj = 0; tj < 8; ++tj)
            acc[ti][tj] = (f32x4){0.f, 0.f, 0.f, 0.f};

    const int nt = kPerSplit / 32;
    int cur = 0;

    // prologue: stage buffer 0 (256 rows of yT16, k-slice k0)
    {
#pragma unroll
        for (int i = 0; i < 4; ++i) {
            int r0 = wave * 64 + i * 16;
            int r  = r0 + (lane >> 2);
            int c  = (lane & 3) ^ ((r >> 1) & 3);
            async_copy16(Y + (size_t)r * NN + k0 + c * 8,
                         (char*)Bs[0] + r0 * 64);
        }
    }

    for (int t = 0; t < nt; ++t) {
        __syncthreads();
        if (t + 1 < nt) {
            int kc = k0 + (t + 1) * 32;
#pragma unroll
            for (int i = 0; i < 4; ++i) {
                int r0 = wave * 64 + i * 16;
                int r  = r0 + (lane >> 2);
                int c  = (lane & 3) ^ ((r >> 1) & 3);
                async_copy16(Y + (size_t)r * NN + kc + c * 8,
                             (char*)Bs[cur ^ 1] + r0 * 64);
            }
        }
        const int kc = k0 + t * 32;

        // stream A (a, f32) -> f16 fragments
        f16x8 af[4];
#pragma unroll
        for (int j = 0; j < 4; ++j) {
            const float* g = A + (size_t)(bm + wm + j * 16 + l16) * NN + kc + quad * 8;
            f32x4 u0 = *(const f32x4*)g;
            f32x4 u1 = *(const f32x4*)(g + 4);
            af[j] = cvt_f32x8_to_f16x8(u0, u1);
        }
        // B fragments from swizzled LDS
        f16x8 bf[8];
#pragma unroll
        for (int j = 0; j < 8; ++j) {
            int row = wn + j * 16 + l16;
            int p   = quad ^ ((row >> 1) & 3);
            bf[j] = *(const f16x8*)(&Bs[cur][0] + row * 32 + p * 8);
        }
#pragma unroll
        for (int ti = 0; ti < 4; ++ti)
#pragma unroll
            for (int tj = 0; tj < 8; ++tj)
                acc[ti][tj] = __builtin_amdgcn_mfma_f32_16x16x32_f16(
                    af[ti], bf[tj], acc[ti][tj], 0, 0, 0);
        cur ^= 1;
    }

    float* Cz = Cp + (size_t)blockIdx.z * NN * 256;
#pragma unroll
    for (int ti = 0; ti < 4; ++ti)
#pragma unroll
        for (int tj = 0; tj < 8; ++tj)
#pragma unroll
            for (int r = 0; r < 4; ++r) {
                int row = bm + wm + ti * 16 + quad * 4 + r;   // n
                int col = wn + tj * 16 + l16;                 // o
                Cz[(size_t)row * 256 + col] = acc[ti][tj][r];
            }
}

// ---------------------------------------------------------------------------
// yT16[i] = (f16) sum_{z<4} yT_p[z][i]   (i over 256*8192, 8 per thread)
// ---------------------------------------------------------------------------
__global__ void reduce_yT(const float* __restrict__ yTp, __fp16* __restrict__ yT16) {
    size_t base = ((size_t)blockIdx.x * 256 + threadIdx.x) * 8;
    f32x4 s0 = (f32x4){0.f, 0.f, 0.f, 0.f};
    f32x4 s1 = (f32x4){0.f, 0.f, 0.f, 0.f};
#pragma unroll
    for (int z = 0; z < 4; ++z) {
        const float* p = yTp + (size_t)z * YTN + base;
        s0 += *(const f32x4*)p;
        s1 += *(const f32x4*)(p + 4);
    }
    *reinterpret_cast<f16x8*>(&yT16[base]) = cvt_f32x8_to_f16x8(s0, s1);
}

// ---------------------------------------------------------------------------
// out[i] = sum_{z<8} out_p[z][i]   (i over 8192*256, 4 per thread)
// ---------------------------------------------------------------------------
__global__ void reduce_out(const float* __restrict__ op, float* __restrict__ out) {
    size_t base = ((size_t)blockIdx.x * 256 + threadIdx.x) * 4;
    f32x4 s = (f32x4){0.f, 0.f, 0.f, 0.f};
#pragma unroll
    for (int z = 0; z < 8; ++z)
        s += *(const f32x4*)(op + (size_t)z * YTN + base);
    *reinterpret_cast<f32x4*>(&out[base]) = s;
}

// ---------------------------------------------------------------------------
extern "C" void kernel_launch(void* const* d_in, const int* in_sizes, int n_in,
                              void* d_out, int out_size, void* d_ws, size_t ws_size,
                              hipStream_t stream) {
    const float* a  = (const float*)d_in[0];   // [8192][8192]
    const float* x  = (const float*)d_in[1];   // [8192][2048] (k = i*8+r contiguous)
    const float* wb = (const float*)d_in[2];   // [4][256][256]
    const float* wr = (const float*)d_in[3];   // [8][4]
    float* out = (float*)d_out;                // [8192][256]

    // ws layout (101 MB total):
    //   [0,   32MB)  yT_p   : 4 x [256][8192] fp32 partials
    //   [32,  36MB)  yT16   : [256][8192] f16
    //   [36, 100MB)  out_p  : 8 x [8192][256] fp32 partials
    //   [100,101MB)  W2T16  : [256][2048] f16
    char* w = (char*)d_ws;
    float*  yT_p  = (float*)(w);
    __fp16* yT16  = (__fp16*)(w + ((size_t)32 << 20));
    float*  out_p = (float*)(w + ((size_t)36 << 20));
    __fp16* W2T16 = (__fp16*)(w + ((size_t)100 << 20));

    // 1) basis-combined weights, f16, [o][k]
    build_w2t16<<<dim3(256), dim3(256), 0, stream>>>(wb, wr, W2T16);

    // 2) yT_p[z][o][m] = W2T16[o][:] . x[m][:]   M=256,N=8192,K=2048, split 4
    gemm1_xstream<<<dim3(2, 64, 4), dim3(256), 0, stream>>>(W2T16, x, yT_p, 512);

    // 3) yT16 = f16(sum_z yT_p)
    reduce_yT<<<dim3(1024), dim3(256), 0, stream>>>(yT_p, yT16);

    // 4) out_p[z][n][o] = a[n][:] . yT16[o][:]   M=8192,N=256(full),K=8192, split 8
    gemm2_astream<<<dim3(64, 1, 8), dim3(256), 0, stream>>>(a, yT16, out_p, 1024);

    // 5) out = sum_z out_p
    reduce_out<<<dim3(2048), dim3(256), 0, stream>>>(out_p, out);
}

// Round 3
// 468.517 us; speedup vs baseline: 1.1658x; 1.1658x over previous
//
#include <hip/hip_runtime.h>
#include <stdint.h>

typedef __fp16 f16x2 __attribute__((ext_vector_type(2)));
typedef __fp16 f16x8 __attribute__((ext_vector_type(8)));
typedef float  f32x4 __attribute__((ext_vector_type(4)));

#define GLOBAL_AS __attribute__((address_space(1)))
#define LDS_AS    __attribute__((address_space(3)))

#define NN   8192
#define INC  256
#define OUTC 256
#define K2   2048                    // INC * RR
#define YTN  ((size_t)OUTC * NN)     // 2M elements

__device__ __forceinline__ void async_copy16(const void* g, void* l) {
    // 16B per lane; LDS dest = wave-uniform base + lane*16 (m97/m104 semantics)
    __builtin_amdgcn_global_load_lds((const GLOBAL_AS uint32_t*)g,
                                     (LDS_AS uint32_t*)l, 16, 0, 0);
}

__device__ __forceinline__ f16x8 cvt_f32x8_to_f16x8(f32x4 u0, f32x4 u1) {
    f16x8 out;
    f16x2* p = (f16x2*)&out;
    p[0] = __builtin_amdgcn_cvt_pkrtz(u0[0], u0[1]);
    p[1] = __builtin_amdgcn_cvt_pkrtz(u0[2], u0[3]);
    p[2] = __builtin_amdgcn_cvt_pkrtz(u1[0], u1[1]);
    p[3] = __builtin_amdgcn_cvt_pkrtz(u1[2], u1[3]);
    return out;
}

// ---------------------------------------------------------------------------
// W2T16[o][k] = sum_b w_rel[r,b] * w_bases[b,i,o],  k = i*8+r, f16 output.
// ---------------------------------------------------------------------------
__global__ void build_w2t16(const float* __restrict__ wb, const float* __restrict__ wr,
                            __fp16* __restrict__ W2T16) {
    int o = blockIdx.x;      // 0..255
    int i = threadIdx.x;     // 0..255
    float s[8];
#pragma unroll
    for (int r = 0; r < 8; ++r) s[r] = 0.f;
#pragma unroll
    for (int b = 0; b < 4; ++b) {
        float w = wb[((size_t)((b << 8) + i)) * OUTC + o];
#pragma unroll
        for (int r = 0; r < 8; ++r) s[r] = fmaf(wr[r * 4 + b], w, s[r]);
    }
    f16x8 out;
    f16x2* p = (f16x2*)&out;
    p[0] = __builtin_amdgcn_cvt_pkrtz(s[0], s[1]);
    p[1] = __builtin_amdgcn_cvt_pkrtz(s[2], s[3]);
    p[2] = __builtin_amdgcn_cvt_pkrtz(s[4], s[5]);
    p[3] = __builtin_amdgcn_cvt_pkrtz(s[6], s[7]);
    *reinterpret_cast<f16x8*>(&W2T16[(size_t)o * K2 + i * 8]) = out;
}

// ---------------------------------------------------------------------------
// GEMM1: yT_p[z][o][m] = W2T16[o][:] . x[m][:]   (M=256 o, N=8192 m, K=2048)
//   A = W2T16 f16 [256][2048]  -> LDS dbuf, XOR-swizzle ((r>>1)&3) on 16B chunks
//   B = x      f32 [8192][2048] -> LDS dbuf (as f32), XOR-swizzle (r&7), cvt@read
// Tile 128x128x32, 4 waves (2x2), wave tile 64x64, acc[4][4].
// Schedule: stage(t+1) BEFORE compute(t); ONE vmcnt(0)+barrier at bottom
// (minimum-2-phase, m248v2). global_load_lds is fire-and-forget, so the
// t+1 staging latency hides under compute(t).
// ---------------------------------------------------------------------------
__global__ __launch_bounds__(256, 2)
void gemm1_v3(const __fp16* __restrict__ W2, const float* __restrict__ X,
              float* __restrict__ Cp, int kPerSplit) {
    __shared__ __align__(16) __fp16 As[2][128 * 32];   //  8KB x2
    __shared__ __align__(16) float  Bs[2][128 * 32];   // 16KB x2

    const int bm = blockIdx.x * 128;   // o
    const int bn = blockIdx.y * 128;   // m
    const int k0 = blockIdx.z * kPerSplit;

    const int tid  = threadIdx.x;
    const int lane = tid & 63;
    const int wave = tid >> 6;
    const int wm   = (wave >> 1) * 64;
    const int wn   = (wave & 1) * 64;
    const int quad = lane >> 4;
    const int l16  = lane & 15;

    f32x4 acc[4][4];
#pragma unroll
    for (int ti = 0; ti < 4; ++ti)
#pragma unroll
        for (int tj = 0; tj < 4; ++tj)
            acc[ti][tj] = (f32x4){0.f, 0.f, 0.f, 0.f};

    const int nt = kPerSplit / 32;

    // --- staging helpers (pre-swizzled GLOBAL source, linear LDS dest) ---
    auto stageA = [&](int buf, int kc) {   // 128 rows x 32 f16
#pragma unroll
        for (int i = 0; i < 2; ++i) {
            int r0 = wave * 32 + i * 16;
            int r  = r0 + (lane >> 2);
            int c  = (lane & 3) ^ ((r >> 1) & 3);
            async_copy16(W2 + (size_t)(bm + r) * K2 + kc + c * 8,
                         (char*)As[buf] + r0 * 64);
        }
    };
    auto stageB = [&](int buf, int kc) {   // 128 rows x 32 f32
#pragma unroll
        for (int i = 0; i < 4; ++i) {
            int r0 = wave * 32 + i * 8;
            int r  = r0 + (lane >> 3);
            int c  = (lane & 7) ^ (r & 7);
            async_copy16(X + (size_t)(bn + r) * K2 + kc + (c << 2),
                         (char*)Bs[buf] + r0 * 128);
        }
    };

    stageA(0, k0);
    stageB(0, k0);
    __syncthreads();          // drain prologue staging

    int cur = 0;
    for (int t = 0; t < nt; ++t) {
        if (t + 1 < nt) {     // issue next-tile staging FIRST (overlaps compute)
            int kc = k0 + (t + 1) * 32;
            stageA(cur ^ 1, kc);
            stageB(cur ^ 1, kc);
        }
        // A fragments (f16, swizzled)
        f16x8 af[4];
#pragma unroll
        for (int j = 0; j < 4; ++j) {
            int row = wm + j * 16 + l16;
            int p   = quad ^ ((row >> 1) & 3);
            af[j] = *(const f16x8*)(&As[cur][0] + row * 32 + p * 8);
        }
        // B fragments (f32, swizzled, cvt to f16)
        f16x8 bf[4];
#pragma unroll
        for (int j = 0; j < 4; ++j) {
            int row = wn + j * 16 + l16;
            int p0  = (2 * quad)     ^ (row & 7);
            int p1  = (2 * quad + 1) ^ (row & 7);
            f32x4 u0 = *(const f32x4*)(&Bs[cur][0] + row * 32 + p0 * 4);
            f32x4 u1 = *(const f32x4*)(&Bs[cur][0] + row * 32 + p1 * 4);
            bf[j] = cvt_f32x8_to_f16x8(u0, u1);
        }
#pragma unroll
        for (int ti = 0; ti < 4; ++ti)
#pragma unroll
            for (int tj = 0; tj < 4; ++tj)
                acc[ti][tj] = __builtin_amdgcn_mfma_f32_16x16x32_f16(
                    af[ti], bf[tj], acc[ti][tj], 0, 0, 0);
        __syncthreads();      // single drain point: vmcnt(0)+lgkmcnt(0)+barrier
        cur ^= 1;
    }

    float* Cz = Cp + (size_t)blockIdx.z * 256 * NN;
#pragma unroll
    for (int ti = 0; ti < 4; ++ti)
#pragma unroll
        for (int tj = 0; tj < 4; ++tj)
#pragma unroll
            for (int r = 0; r < 4; ++r) {
                int row = bm + wm + ti * 16 + quad * 4 + r;   // o
                int col = bn + wn + tj * 16 + l16;            // m
                Cz[(size_t)row * NN + col] = acc[ti][tj][r];
            }
}

// ---------------------------------------------------------------------------
// GEMM2: out_p[z][n][o] = a[n][:] . yT16[o][:]   (M=8192 n, N=256 o, K=8192)
//   A = a    f32 [8192][8192] -> LDS dbuf (as f32), XOR-swizzle (r&7), cvt@read
//   B = yT16 f16 [256][8192]  -> LDS dbuf, XOR-swizzle ((r>>1)&3), full N
// Tile 128x256x32, 4 waves, wave tile 64x128, acc[4][8]. Same schedule.
// LDS = 32KB A + 32KB B = 64KB -> 2 blocks/CU. grid 64x1x8 = 512 = 2/CU.
// ---------------------------------------------------------------------------
__global__ __launch_bounds__(256, 2)
void gemm2_v3(const float* __restrict__ A, const __fp16* __restrict__ Y,
              float* __restrict__ Cp, int kPerSplit) {
    __shared__ __align__(16) float  As[2][128 * 32];   // 16KB x2
    __shared__ __align__(16) __fp16 Bs[2][256 * 32];   // 16KB x2

    const int bm = blockIdx.x * 128;   // n
    const int k0 = blockIdx.z * kPerSplit;

    const int tid  = threadIdx.x;
    const int lane = tid & 63;
    const int wave = tid >> 6;
    const int wm   = (wave >> 1) * 64;    // 0 / 64
    const int wn   = (wave & 1) * 128;    // 0 / 128
    const int quad = lane >> 4;
    const int l16  = lane & 15;

    f32x4 acc[4][8];
#pragma unroll
    for (int ti = 0; ti < 4; ++ti)
#pragma unroll
        for (int tj = 0; tj < 8; ++tj)
            acc[ti][tj] = (f32x4){0.f, 0.f, 0.f, 0.f};

    const int nt = kPerSplit / 32;

    auto stageA = [&](int buf, int kc) {   // 128 rows x 32 f32
#pragma unroll
        for (int i = 0; i < 4; ++i) {
            int r0 = wave * 32 + i * 8;
            int r  = r0 + (lane >> 3);
            int c  = (lane & 7) ^ (r & 7);
            async_copy16(A + (size_t)(bm + r) * NN + kc + (c << 2),
                         (char*)As[buf] + r0 * 128);
        }
    };
    auto stageB = [&](int buf, int kc) {   // 256 rows x 32 f16
#pragma unroll
        for (int i = 0; i < 4; ++i) {
            int r0 = wave * 64 + i * 16;
            int r  = r0 + (lane >> 2);
            int c  = (lane & 3) ^ ((r >> 1) & 3);
            async_copy16(Y + (size_t)r * NN + kc + c * 8,
                         (char*)Bs[buf] + r0 * 64);
        }
    };

    stageA(0, k0);
    stageB(0, k0);
    __syncthreads();

    int cur = 0;
    for (int t = 0; t < nt; ++t) {
        if (t + 1 < nt) {
            int kc = k0 + (t + 1) * 32;
            stageA(cur ^ 1, kc);
            stageB(cur ^ 1, kc);
        }
        // A fragments (f32, swizzled, cvt)
        f16x8 af[4];
#pragma unroll
        for (int j = 0; j < 4; ++j) {
            int row = wm + j * 16 + l16;
            int p0  = (2 * quad)     ^ (row & 7);
            int p1  = (2 * quad + 1) ^ (row & 7);
            f32x4 u0 = *(const f32x4*)(&As[cur][0] + row * 32 + p0 * 4);
            f32x4 u1 = *(const f32x4*)(&As[cur][0] + row * 32 + p1 * 4);
            af[j] = cvt_f32x8_to_f16x8(u0, u1);
        }
        // B fragments (f16, swizzled)
        f16x8 bf[8];
#pragma unroll
        for (int j = 0; j < 8; ++j) {
            int row = wn + j * 16 + l16;
            int p   = quad ^ ((row >> 1) & 3);
            bf[j] = *(const f16x8*)(&Bs[cur][0] + row * 32 + p * 8);
        }
#pragma unroll
        for (int ti = 0; ti < 4; ++ti)
#pragma unroll
            for (int tj = 0; tj < 8; ++tj)
                acc[ti][tj] = __builtin_amdgcn_mfma_f32_16x16x32_f16(
                    af[ti], bf[tj], acc[ti][tj], 0, 0, 0);
        __syncthreads();
        cur ^= 1;
    }

    float* Cz = Cp + (size_t)blockIdx.z * NN * 256;
#pragma unroll
    for (int ti = 0; ti < 4; ++ti)
#pragma unroll
        for (int tj = 0; tj < 8; ++tj)
#pragma unroll
            for (int r = 0; r < 4; ++r) {
                int row = bm + wm + ti * 16 + quad * 4 + r;   // n
                int col = wn + tj * 16 + l16;                 // o
                Cz[(size_t)row * 256 + col] = acc[ti][tj][r];
            }
}

// ---------------------------------------------------------------------------
// yT16[i] = (f16) sum_{z<4} yT_p[z][i]
// ---------------------------------------------------------------------------
__global__ void reduce_yT(const float* __restrict__ yTp, __fp16* __restrict__ yT16) {
    size_t base = ((size_t)blockIdx.x * 256 + threadIdx.x) * 8;
    f32x4 s0 = (f32x4){0.f, 0.f, 0.f, 0.f};
    f32x4 s1 = (f32x4){0.f, 0.f, 0.f, 0.f};
#pragma unroll
    for (int z = 0; z < 4; ++z) {
        const float* p = yTp + (size_t)z * YTN + base;
        s0 += *(const f32x4*)p;
        s1 += *(const f32x4*)(p + 4);
    }
    *reinterpret_cast<f16x8*>(&yT16[base]) = cvt_f32x8_to_f16x8(s0, s1);
}

// ---------------------------------------------------------------------------
// out[i] = sum_{z<8} out_p[z][i]
// ---------------------------------------------------------------------------
__global__ void reduce_out(const float* __restrict__ op, float* __restrict__ out) {
    size_t base = ((size_t)blockIdx.x * 256 + threadIdx.x) * 4;
    f32x4 s = (f32x4){0.f, 0.f, 0.f, 0.f};
#pragma unroll
    for (int z = 0; z < 8; ++z)
        s += *(const f32x4*)(op + (size_t)z * YTN + base);
    *reinterpret_cast<f32x4*>(&out[base]) = s;
}

// ---------------------------------------------------------------------------
extern "C" void kernel_launch(void* const* d_in, const int* in_sizes, int n_in,
                              void* d_out, int out_size, void* d_ws, size_t ws_size,
                              hipStream_t stream) {
    const float* a  = (const float*)d_in[0];   // [8192][8192]
    const float* x  = (const float*)d_in[1];   // [8192][2048] (k = i*8+r contiguous)
    const float* wb = (const float*)d_in[2];   // [4][256][256]
    const float* wr = (const float*)d_in[3];   // [8][4]
    float* out = (float*)d_out;                // [8192][256]

    // ws layout (101 MB total):
    //   [0,   32MB)  yT_p   : 4 x [256][8192] fp32 partials
    //   [32,  36MB)  yT16   : [256][8192] f16
    //   [36, 100MB)  out_p  : 8 x [8192][256] fp32 partials
    //   [100,101MB)  W2T16  : [256][2048] f16
    char* w = (char*)d_ws;
    float*  yT_p  = (float*)(w);
    __fp16* yT16  = (__fp16*)(w + ((size_t)32 << 20));
    float*  out_p = (float*)(w + ((size_t)36 << 20));
    __fp16* W2T16 = (__fp16*)(w + ((size_t)100 << 20));

    // 1) basis-combined weights, f16, [o][k]
    build_w2t16<<<dim3(256), dim3(256), 0, stream>>>(wb, wr, W2T16);

    // 2) yT_p[z][o][m] = W2T16[o][:] . x[m][:]   M=256,N=8192,K=2048, split 4
    gemm1_v3<<<dim3(2, 64, 4), dim3(256), 0, stream>>>(W2T16, x, yT_p, 512);

    // 3) yT16 = f16(sum_z yT_p)
    reduce_yT<<<dim3(1024), dim3(256), 0, stream>>>(yT_p, yT16);

    // 4) out_p[z][n][o] = a[n][:] . yT16[o][:]   M=8192,N=256(full),K=8192, split 8
    gemm2_v3<<<dim3(64, 1, 8), dim3(256), 0, stream>>>(a, yT16, out_p, 1024);

    // 5) out = sum_z out_p
    reduce_out<<<dim3(2048), dim3(256), 0, stream>>>(out_p, out);
}